// Round 3
// baseline (269.149 us; speedup 1.0000x reference)
//
#include <hip/hip_runtime.h>

#define NLAYER 4
#define BATCH  256
#define HID    1024

typedef float f32x4 __attribute__((ext_vector_type(4)));
typedef short short8 __attribute__((ext_vector_type(8)));
typedef unsigned short ushort_t;
typedef unsigned long long u64;

// Raw sync primitives (round-0 proven discipline). All counted VM ops (DMA
// builtin + GLD16 asm) and WAITV/BAR are volatile -> mutual program order.
#define BAR()     asm volatile("s_barrier")
#define WAITV(n)  asm volatile("s_waitcnt vmcnt(" #n ")")
#define WAITV_TIE2(n, x, y) \
  asm volatile("s_waitcnt vmcnt(" #n ")" : "+v"(x), "+v"(y))
#define DSR(d, a) asm volatile("ds_read_b128 %0, %1" : "=v"(d) : "v"(a))
#define LGKM0_TIE4(a,b,c,d) \
  asm volatile("s_waitcnt lgkmcnt(0)" : "+v"(a),"+v"(b),"+v"(c),"+v"(d))
#define FULLBAR() asm volatile("s_waitcnt vmcnt(0) lgkmcnt(0)\ns_barrier" ::: "memory")
#define GLD16(d, a) asm volatile("global_load_dwordx4 %0, %1, off" : "=v"(d) : "v"(a))

__device__ __forceinline__ unsigned short f2bf(float f) {
  unsigned int u = __float_as_uint(f);
  unsigned int r = u + 0x7fffu + ((u >> 16) & 1u);  // RNE
  return (unsigned short)(r >> 16);
}
__device__ __forceinline__ float sigm(float x) { return 1.f / (1.f + __expf(-x)); }
__device__ __forceinline__ float tanh_(float x) { return 2.f / (1.f + __expf(-2.f * x)) - 1.f; }

__device__ __forceinline__ void dma16(const void* g, void* l) {
  __builtin_amdgcn_global_load_lds(
      (const __attribute__((address_space(1))) unsigned int*)g,
      (__attribute__((address_space(3))) unsigned int*)l, 16, 0, 0);
}

// Packed tile format (64x64 tile = 8KB): logical (r 0..63, c 0..7 16B-chunks)
// at chunk = (r>>3)*64 + (r&7)*8 + ((c^r)&7). Wpk layer layout: ushort offset
// ((nb*32 + kt)*4096) + g*512 + i*8 + j, kt 0..15 = w_ih, 16..31 = w_hh.
// Inverse map (chunk q -> source): i=q&63, g=(q>>6)&7, kt=(q>>9)&31, nb=q>>14;
// r=g*8+(i>>3); c=(i&7)^(r&7); Wrow=(r>>4)*1024+nb*16+(r&15); k=(kt&15)*64+c*8.
// Pack pattern: store LINEAR 16B per chunk, gather-read 2x16B (wave reads land
// as 8 rows x 256B contiguous segments -> both sides coalesce).

__device__ __forceinline__ void pack_chunks(const float* __restrict__ win,
                                            const float* __restrict__ whn,
                                            ushort_t* __restrict__ dst,
                                            int q) {
  int i = q & 63, g = (q >> 6) & 7, kt = (q >> 9) & 31, nbq = q >> 14;
  int r = g * 8 + (i >> 3);
  int c = (i & 7) ^ (r & 7);
  const float* src = ((kt >> 4) ? whn : win)
      + ((size_t)((r >> 4) * 1024 + nbq * 16 + (r & 15)) << 10)
      + ((kt & 15) * 64 + c * 8);
  float4 v0 = ((const float4*)src)[0], v1 = ((const float4*)src)[1];
  short8 pk;
  pk[0] = (short)f2bf(v0.x); pk[1] = (short)f2bf(v0.y);
  pk[2] = (short)f2bf(v0.z); pk[3] = (short)f2bf(v0.w);
  pk[4] = (short)f2bf(v1.x); pk[5] = (short)f2bf(v1.y);
  pk[6] = (short)f2bf(v1.z); pk[7] = (short)f2bf(v1.w);
  *(short8*)(dst + (size_t)q * 8) = pk;
}

// ---- init: pack A (blocks 0..639, unchanged from verified rounds) + pack W
// layer 0 (blocks 640..4735, one chunk per thread, linear stores). ----
__global__ __launch_bounds__(256) void pack_init(
    const float* __restrict__ x, const float* __restrict__ h0,
    const float* __restrict__ w_ih, const float* __restrict__ w_hh,
    ushort_t* __restrict__ wpk, ushort_t* __restrict__ apk) {
  int blk = blockIdx.x;
  if (blk >= 640) {
    int q = (blk - 640) * 256 + threadIdx.x;   // 0..1048575
    pack_chunks(w_ih, w_hh, wpk, q);
    return;
  }
  int t = blk * 256 + threadIdx.x;  // 0..163839
  int lane = t & 63;
  int r8 = lane >> 3;
  int c = (lane & 7) ^ r8;
  const float* src;
  ushort_t* dst;
  if (t < 32768) {
    int g = (t >> 6) & 7, kt = (t >> 9) & 15, mb = t >> 13;
    int m = mb * 64 + g * 8 + r8;
    src = x + (size_t)m * 1024 + kt * 64 + c * 8;
    dst = apk + (size_t)mb * 131072 + (size_t)kt * 4096 + g * 512 + lane * 8;
  } else {
    int u = t - 32768;
    int g = (u >> 6) & 7, kt16 = (u >> 9) & 15, mb = (u >> 13) & 3, l = u >> 15;
    int m = mb * 64 + g * 8 + r8;
    src = h0 + (size_t)l * 262144 + (size_t)m * 1024 + kt16 * 64 + c * 8;
    dst = apk + (size_t)l * 524288 + (size_t)mb * 131072
        + (size_t)(16 + kt16) * 4096 + g * 512 + lane * 8;
  }
  float4 a = *(const float4*)src, b = *(const float4*)(src + 4);
  short8 pk;
  pk[0] = (short)f2bf(a.x); pk[1] = (short)f2bf(a.y);
  pk[2] = (short)f2bf(a.z); pk[3] = (short)f2bf(a.w);
  pk[4] = (short)f2bf(b.x); pk[5] = (short)f2bf(b.y);
  pk[6] = (short)f2bf(b.z); pk[7] = (short)f2bf(b.w);
  *(short8*)dst = pk;
}

// ---- fused layer GEMM: blockIdx.y<4 = verified round-0 body BYTE-IDENTICAL
// (B via DMA->LDS quad-buffer, A-frags from L2, exact vmcnt counting, LSTM
// epilogue). blockIdx.y==4 = 64 independent pack workgroups that pack the
// NEXT layer's weights with plain C code (no barriers, no shared state) on
// the GEMM's idle bandwidth, then exit. ----
__global__ __launch_bounds__(512) void lstm_fused(
    const ushort_t* __restrict__ apk, const ushort_t* __restrict__ wpk,
    const float* __restrict__ bi, const float* __restrict__ bh,
    const float* __restrict__ c0l,
    float* __restrict__ hout, float* __restrict__ cout,
    ushort_t* __restrict__ apk_next,
    const float* __restrict__ win, const float* __restrict__ whn,
    ushort_t* __restrict__ wpk_next) {
  __shared__ union U {
    ushort_t stage[4][4096];   // 4 x 8KB B tiles
    float sg[4 * 64 * 17];     // epilogue gate exchange (17.4KB, fits)
  } sm;

  const int tid = threadIdx.x;

  if (blockIdx.y == 4) {       // ---- pack-producer workgroups ----
    if (wpk_next) {
      int t0 = blockIdx.x * 512 + tid;   // 0..32767
#pragma unroll 4
      for (int k = 0; k < 32; ++k)
        pack_chunks(win, whn, wpk_next, t0 + k * 32768);
    }
    return;
  }

  const int nb = blockIdx.x;   // 0..63
  const int mb = blockIdx.y;   // 0..3
  const int h0c = nb * 16;
  const int m0 = mb * 64;
  const int lane = tid & 63;
  const int w = tid >> 6;
  const int wm = w & 3, wcol = w >> 2;
  const int lrow = lane & 15, lq = lane >> 4;

  // B DMA source: wave w deposits group w (1KB) of each 8KB B tile
  const char* srcB = (const char*)(wpk + (size_t)nb * 131072 + w * 512 + lane * 8);

  // A gather addresses (bytes), advance 8192/tile
  const int rA = wm * 16 + lrow;
#define CHUNK(r, c) (((r) >> 3) * 64 + ((r) & 7) * 8 + (((c) ^ (r)) & 7))
  u64 aA0 = (u64)(const char*)(apk + (size_t)mb * 131072 + CHUNK(rA, lq) * 8);
  u64 aA1 = (u64)(const char*)(apk + (size_t)mb * 131072 + CHUNK(rA, 4 + lq) * 8);

  // B fragment LDS byte addresses
  unsigned smb = (unsigned)(uintptr_t)(__attribute__((address_space(3))) void*)&sm;
  const int rB0 = wcol * 32 + lrow, rB1 = rB0 + 16;
  unsigned oB00 = smb + CHUNK(rB0, lq) * 16, oB01 = smb + CHUNK(rB0, 4 + lq) * 16;
  unsigned oB10 = smb + CHUNK(rB1, lq) * 16, oB11 = smb + CHUNK(rB1, 4 + lq) * 16;
#undef CHUNK

  f32x4 acc0 = {0.f, 0.f, 0.f, 0.f}, acc1 = {0.f, 0.f, 0.f, 0.f};
  short8 areg[4][2];

  // prologue: tiles 0,1,2 -> issue order per tile: D, Aa, Ab
#pragma unroll
  for (int t = 0; t < 3; ++t) {
    dma16(srcB, &sm.stage[t][w * 512]);
    srcB += 8192;
    GLD16(areg[t][0], aA0); aA0 += 8192;
    GLD16(areg[t][1], aA1); aA1 += 8192;
  }

#define KSTEP(S, PRE, POST, ISSUE)                                          \
  {                                                                         \
    WAITV(PRE);                                                             \
    BAR();                                                                  \
    if (ISSUE) {                                                            \
      dma16(srcB, &sm.stage[(S + 3) & 3][w * 512]);                         \
      srcB += 8192;                                                         \
      GLD16(areg[(S + 3) & 3][0], aA0); aA0 += 8192;                        \
      GLD16(areg[(S + 3) & 3][1], aA1); aA1 += 8192;                        \
    }                                                                       \
    WAITV_TIE2(POST, areg[S][0], areg[S][1]);                               \
    short8 b00, b01, b10, b11;                                              \
    DSR(b00, oB00 + (S) * 8192u); DSR(b10, oB10 + (S) * 8192u);             \
    DSR(b01, oB01 + (S) * 8192u); DSR(b11, oB11 + (S) * 8192u);             \
    LGKM0_TIE4(b00, b01, b10, b11);                                         \
    acc0 = __builtin_amdgcn_mfma_f32_16x16x32_bf16(areg[S][0], b00, acc0, 0, 0, 0); \
    acc1 = __builtin_amdgcn_mfma_f32_16x16x32_bf16(areg[S][0], b10, acc1, 0, 0, 0); \
    acc0 = __builtin_amdgcn_mfma_f32_16x16x32_bf16(areg[S][1], b01, acc0, 0, 0, 0); \
    acc1 = __builtin_amdgcn_mfma_f32_16x16x32_bf16(areg[S][1], b11, acc1, 0, 0, 0); \
  }

  // kt = 0..27 (7 x 4, slots static), then peeled 28..31 with exact tail waits
  for (int i = 0; i < 7; ++i) {
    KSTEP(0, 8, 9, 1)
    KSTEP(1, 8, 9, 1)
    KSTEP(2, 8, 9, 1)
    KSTEP(3, 8, 9, 1)
  }
  KSTEP(0, 8, 9, 1)   // kt=28, issues tile 31
  KSTEP(1, 8, 6, 0)   // kt=29
  KSTEP(2, 5, 3, 0)   // kt=30
  KSTEP(3, 2, 0, 0)   // kt=31
#undef KSTEP

  FULLBAR();  // vmcnt already 0; drain LDS, then overlay sg over stage

  // acc layout (verified): row = m0 + wm*16 + lq*4 + r, gate = wcol*2+nt, hcol = lrow
#pragma unroll
  for (int nt = 0; nt < 2; ++nt) {
    int gate = wcol * 2 + nt;
    int rowb = wm * 16 + lq * 4;
    const f32x4& a = nt ? acc1 : acc0;
#pragma unroll
    for (int r = 0; r < 4; ++r)
      sm.sg[gate * 1088 + (rowb + r) * 17 + lrow] = a[r];
  }
  FULLBAR();

  {
    const int erow = tid >> 3, ehp = (tid & 7) * 2;
    // epilogue-only global loads: issued after all counted VM ops (safe)
    float2 cp = *(const float2*)(c0l + (size_t)(m0 + erow) * 1024 + h0c + ehp);
    float cpa[2] = {cp.x, cp.y};
    float hva[2], cva[2];
#pragma unroll
    for (int e = 0; e < 2; ++e) {
      int hc = ehp + e;
      float gi = sm.sg[0 * 1088 + erow * 17 + hc] + bi[h0c + hc]          + bh[h0c + hc];
      float gf = sm.sg[1 * 1088 + erow * 17 + hc] + bi[1024 + h0c + hc]   + bh[1024 + h0c + hc];
      float gg = sm.sg[2 * 1088 + erow * 17 + hc] + bi[2048 + h0c + hc]   + bh[2048 + h0c + hc];
      float go = sm.sg[3 * 1088 + erow * 17 + hc] + bi[3072 + h0c + hc]   + bh[3072 + h0c + hc];
      float cn = sigm(gf) * cpa[e] + sigm(gi) * tanh_(gg);
      cva[e] = cn;
      hva[e] = sigm(go) * tanh_(cn);
    }
    float2 hv; hv.x = hva[0]; hv.y = hva[1];
    float2 cv; cv.x = cva[0]; cv.y = cva[1];
    *(float2*)(hout + (size_t)(m0 + erow) * 1024 + h0c + ehp) = hv;
    *(float2*)(cout + (size_t)(m0 + erow) * 1024 + h0c + ehp) = cv;
    if (apk_next) {  // packed bf16 h for next layer's A gathers
      int g = erow >> 3;
#pragma unroll
      for (int e = 0; e < 2; ++e) {
        int k = h0c + ehp + e;
        int cc = (k >> 3) & 7, j = k & 7;
        int i = (erow & 7) * 8 + ((cc ^ erow) & 7);
        apk_next[(size_t)mb * 131072 + (size_t)(k >> 6) * 4096 + g * 512 + i * 8 + j] =
            f2bf(hva[e]);
      }
    }
  }
}

extern "C" void kernel_launch(void* const* d_in, const int* in_sizes, int n_in,
                              void* d_out, int out_size, void* d_ws, size_t ws_size,
                              hipStream_t stream) {
  const float* x    = (const float*)d_in[0];
  const float* h0   = (const float*)d_in[1];
  const float* c0   = (const float*)d_in[2];
  const float* w_ih = (const float*)d_in[3];
  const float* w_hh = (const float*)d_in[4];
  const float* b_ih = (const float*)d_in[5];
  const float* b_hh = (const float*)d_in[6];
  float* out = (float*)d_out;

  ushort_t* Wpk = (ushort_t*)d_ws;              // 4 layers x 16 MB packed bf16 W
  ushort_t* Apk = Wpk + (size_t)4 * 8388608;    // 4 layers x 1 MB packed bf16 A

  // init: pack A (640 blocks) + pack layer-0 weights (4096 blocks)
  pack_init<<<4736, 256, 0, stream>>>(x, h0, w_ih, w_hh, Wpk, Apk);

  const size_t BH = (size_t)BATCH * HID;
  for (int l = 0; l < NLAYER; ++l) {
    int nl = l + 1;
    lstm_fused<<<dim3(64, 5), 512, 0, stream>>>(
        Apk + (size_t)l * 524288, Wpk + (size_t)l * 8388608,
        b_ih + (size_t)l * 4096, b_hh + (size_t)l * 4096,
        c0 + (size_t)l * BH,
        out + (size_t)l * BH, out + (size_t)NLAYER * BH + (size_t)l * BH,
        (l < NLAYER - 1) ? Apk + (size_t)nl * 524288 : (ushort_t*)nullptr,
        w_ih + (size_t)(l < NLAYER - 1 ? nl : 0) * 4194304,
        w_hh + (size_t)(l < NLAYER - 1 ? nl : 0) * 4194304,
        (l < NLAYER - 1) ? Wpk + (size_t)nl * 8388608 : (ushort_t*)nullptr);
  }
}

// Round 4
// 218.308 us; speedup vs baseline: 1.2329x; 1.2329x over previous
//
#include <hip/hip_runtime.h>

#define NLAYER 4
#define BATCH  256
#define HID    1024

typedef float f32x4 __attribute__((ext_vector_type(4)));
typedef short short8 __attribute__((ext_vector_type(8)));
typedef unsigned short ushort_t;
typedef unsigned long long u64;

// Raw sync primitives (round-0 proven discipline). All counted VM ops (DMA
// builtin + GLD16 asm) and WAITV/BAR are volatile -> mutual program order.
#define BAR()     asm volatile("s_barrier")
#define WAITV(n)  asm volatile("s_waitcnt vmcnt(" #n ")")
#define WAITV_TIE2(n, x, y) \
  asm volatile("s_waitcnt vmcnt(" #n ")" : "+v"(x), "+v"(y))
#define DSR(d, a) asm volatile("ds_read_b128 %0, %1" : "=v"(d) : "v"(a))
#define LGKM0_TIE4(a,b,c,d) \
  asm volatile("s_waitcnt lgkmcnt(0)" : "+v"(a),"+v"(b),"+v"(c),"+v"(d))
#define FULLBAR() asm volatile("s_waitcnt vmcnt(0) lgkmcnt(0)\ns_barrier" ::: "memory")
#define GLD16(d, a) asm volatile("global_load_dwordx4 %0, %1, off" : "=v"(d) : "v"(a))

__device__ __forceinline__ unsigned short f2bf(float f) {
  unsigned int u = __float_as_uint(f);
  unsigned int r = u + 0x7fffu + ((u >> 16) & 1u);  // RNE
  return (unsigned short)(r >> 16);
}
__device__ __forceinline__ float sigm(float x) { return 1.f / (1.f + __expf(-x)); }
__device__ __forceinline__ float tanh_(float x) { return 2.f / (1.f + __expf(-2.f * x)) - 1.f; }

__device__ __forceinline__ void dma16(const void* g, void* l) {
  __builtin_amdgcn_global_load_lds(
      (const __attribute__((address_space(1))) unsigned int*)g,
      (__attribute__((address_space(3))) unsigned int*)l, 16, 0, 0);
}

// Packed tile format (64x64 tile = 8KB): logical (r 0..63, c 0..7 16B-chunks)
// at chunk = (r>>3)*64 + (r&7)*8 + ((c^r)&7). Wpk layer layout: ushort offset
// ((nb*32 + kt)*4096) + g*512 + i*8 + j, kt 0..15 = w_ih, 16..31 = w_hh.
// Inverse map (chunk q -> source): i=q&63, g=(q>>6)&7, kt=(q>>9)&31, nb=q>>14;
// r=g*8+(i>>3); c=(i&7)^(r&7); Wrow=(r>>4)*1024+nb*16+(r&15); k=(kt&15)*64+c*8.
// Pack pattern (verified round 3, ~7x faster than scattered-store pack_w):
// store LINEAR 16B per chunk; gather reads land as 8 rows x 256B contiguous
// segments per wave -> both sides coalesce.

__device__ __forceinline__ void pack_chunks(const float* __restrict__ win,
                                            const float* __restrict__ whn,
                                            ushort_t* __restrict__ dst,
                                            int q) {
  int i = q & 63, g = (q >> 6) & 7, kt = (q >> 9) & 31, nbq = q >> 14;
  int r = g * 8 + (i >> 3);
  int c = (i & 7) ^ (r & 7);
  const float* src = ((kt >> 4) ? whn : win)
      + ((size_t)((r >> 4) * 1024 + nbq * 16 + (r & 15)) << 10)
      + ((kt & 15) * 64 + c * 8);
  float4 v0 = ((const float4*)src)[0], v1 = ((const float4*)src)[1];
  short8 pk;
  pk[0] = (short)f2bf(v0.x); pk[1] = (short)f2bf(v0.y);
  pk[2] = (short)f2bf(v0.z); pk[3] = (short)f2bf(v0.w);
  pk[4] = (short)f2bf(v1.x); pk[5] = (short)f2bf(v1.y);
  pk[6] = (short)f2bf(v1.z); pk[7] = (short)f2bf(v1.w);
  *(short8*)(dst + (size_t)q * 8) = pk;
}

// ---- init: pack A (blocks 0..639, unchanged from verified rounds) + pack W
// for ALL FOUR layers (blocks 640..17023, one chunk per thread, linear
// stores). All inputs are L3-dirty from the harness upload -> ~7 TB/s. ----
__global__ __launch_bounds__(256) void pack_init(
    const float* __restrict__ x, const float* __restrict__ h0,
    const float* __restrict__ w_ih, const float* __restrict__ w_hh,
    ushort_t* __restrict__ wpk, ushort_t* __restrict__ apk) {
  int blk = blockIdx.x;
  if (blk >= 640) {
    int u = blk - 640;                 // 0..16383
    int l = u >> 12;                   // 4096 blocks per layer
    int q = (u & 4095) * 256 + threadIdx.x;   // 0..1048575
    pack_chunks(w_ih + (size_t)l * 4194304, w_hh + (size_t)l * 4194304,
                wpk + (size_t)l * 8388608, q);
    return;
  }
  int t = blk * 256 + threadIdx.x;  // 0..163839
  int lane = t & 63;
  int r8 = lane >> 3;
  int c = (lane & 7) ^ r8;
  const float* src;
  ushort_t* dst;
  if (t < 32768) {
    int g = (t >> 6) & 7, kt = (t >> 9) & 15, mb = t >> 13;
    int m = mb * 64 + g * 8 + r8;
    src = x + (size_t)m * 1024 + kt * 64 + c * 8;
    dst = apk + (size_t)mb * 131072 + (size_t)kt * 4096 + g * 512 + lane * 8;
  } else {
    int u = t - 32768;
    int g = (u >> 6) & 7, kt16 = (u >> 9) & 15, mb = (u >> 13) & 3, l = u >> 15;
    int m = mb * 64 + g * 8 + r8;
    src = h0 + (size_t)l * 262144 + (size_t)m * 1024 + kt16 * 64 + c * 8;
    dst = apk + (size_t)l * 524288 + (size_t)mb * 131072
        + (size_t)(16 + kt16) * 4096 + g * 512 + lane * 8;
  }
  float4 a = *(const float4*)src, b = *(const float4*)(src + 4);
  short8 pk;
  pk[0] = (short)f2bf(a.x); pk[1] = (short)f2bf(a.y);
  pk[2] = (short)f2bf(a.z); pk[3] = (short)f2bf(a.w);
  pk[4] = (short)f2bf(b.x); pk[5] = (short)f2bf(b.y);
  pk[6] = (short)f2bf(b.z); pk[7] = (short)f2bf(b.w);
  *(short8*)dst = pk;
}

// ---- fused layer GEMM: verified round-0 body, grid (64,4) = 1 block/CU,
// ZERO co-residents (round-3 lesson: +25us/dispatch from 64 extra blocks).
// B via DMA->LDS quad-buffer, A-frags gathered from L2 (4 rotating reg
// slots, 3 ahead), exact vmcnt counting, LSTM cell epilogue. ----
__global__ __launch_bounds__(512) void lstm_fused(
    const ushort_t* __restrict__ apk, const ushort_t* __restrict__ wpk,
    const float* __restrict__ bi, const float* __restrict__ bh,
    const float* __restrict__ c0l,
    float* __restrict__ hout, float* __restrict__ cout,
    ushort_t* __restrict__ apk_next) {
  __shared__ union U {
    ushort_t stage[4][4096];   // 4 x 8KB B tiles
    float sg[4 * 64 * 17];     // epilogue gate exchange (17.4KB, fits)
  } sm;

  const int tid = threadIdx.x;
  const int nb = blockIdx.x;   // 0..63
  const int mb = blockIdx.y;   // 0..3
  const int h0c = nb * 16;
  const int m0 = mb * 64;
  const int lane = tid & 63;
  const int w = tid >> 6;
  const int wm = w & 3, wcol = w >> 2;
  const int lrow = lane & 15, lq = lane >> 4;

  // B DMA source: wave w deposits group w (1KB) of each 8KB B tile
  const char* srcB = (const char*)(wpk + (size_t)nb * 131072 + w * 512 + lane * 8);

  // A gather addresses (bytes), advance 8192/tile
  const int rA = wm * 16 + lrow;
#define CHUNK(r, c) (((r) >> 3) * 64 + ((r) & 7) * 8 + (((c) ^ (r)) & 7))
  u64 aA0 = (u64)(const char*)(apk + (size_t)mb * 131072 + CHUNK(rA, lq) * 8);
  u64 aA1 = (u64)(const char*)(apk + (size_t)mb * 131072 + CHUNK(rA, 4 + lq) * 8);

  // B fragment LDS byte addresses
  unsigned smb = (unsigned)(uintptr_t)(__attribute__((address_space(3))) void*)&sm;
  const int rB0 = wcol * 32 + lrow, rB1 = rB0 + 16;
  unsigned oB00 = smb + CHUNK(rB0, lq) * 16, oB01 = smb + CHUNK(rB0, 4 + lq) * 16;
  unsigned oB10 = smb + CHUNK(rB1, lq) * 16, oB11 = smb + CHUNK(rB1, 4 + lq) * 16;
#undef CHUNK

  f32x4 acc0 = {0.f, 0.f, 0.f, 0.f}, acc1 = {0.f, 0.f, 0.f, 0.f};
  short8 areg[4][2];

  // prologue: tiles 0,1,2 -> issue order per tile: D, Aa, Ab
#pragma unroll
  for (int t = 0; t < 3; ++t) {
    dma16(srcB, &sm.stage[t][w * 512]);
    srcB += 8192;
    GLD16(areg[t][0], aA0); aA0 += 8192;
    GLD16(areg[t][1], aA1); aA1 += 8192;
  }

#define KSTEP(S, PRE, POST, ISSUE)                                          \
  {                                                                         \
    WAITV(PRE);                                                             \
    BAR();                                                                  \
    if (ISSUE) {                                                            \
      dma16(srcB, &sm.stage[(S + 3) & 3][w * 512]);                         \
      srcB += 8192;                                                         \
      GLD16(areg[(S + 3) & 3][0], aA0); aA0 += 8192;                        \
      GLD16(areg[(S + 3) & 3][1], aA1); aA1 += 8192;                        \
    }                                                                       \
    WAITV_TIE2(POST, areg[S][0], areg[S][1]);                               \
    short8 b00, b01, b10, b11;                                              \
    DSR(b00, oB00 + (S) * 8192u); DSR(b10, oB10 + (S) * 8192u);             \
    DSR(b01, oB01 + (S) * 8192u); DSR(b11, oB11 + (S) * 8192u);             \
    LGKM0_TIE4(b00, b01, b10, b11);                                         \
    acc0 = __builtin_amdgcn_mfma_f32_16x16x32_bf16(areg[S][0], b00, acc0, 0, 0, 0); \
    acc1 = __builtin_amdgcn_mfma_f32_16x16x32_bf16(areg[S][0], b10, acc1, 0, 0, 0); \
    acc0 = __builtin_amdgcn_mfma_f32_16x16x32_bf16(areg[S][1], b01, acc0, 0, 0, 0); \
    acc1 = __builtin_amdgcn_mfma_f32_16x16x32_bf16(areg[S][1], b11, acc1, 0, 0, 0); \
  }

  // kt = 0..27 (7 x 4, slots static), then peeled 28..31 with exact tail waits
  for (int i = 0; i < 7; ++i) {
    KSTEP(0, 8, 9, 1)
    KSTEP(1, 8, 9, 1)
    KSTEP(2, 8, 9, 1)
    KSTEP(3, 8, 9, 1)
  }
  KSTEP(0, 8, 9, 1)   // kt=28, issues tile 31
  KSTEP(1, 8, 6, 0)   // kt=29
  KSTEP(2, 5, 3, 0)   // kt=30
  KSTEP(3, 2, 0, 0)   // kt=31
#undef KSTEP

  FULLBAR();  // vmcnt already 0; drain LDS, then overlay sg over stage

  // acc layout (verified): row = m0 + wm*16 + lq*4 + r, gate = wcol*2+nt, hcol = lrow
#pragma unroll
  for (int nt = 0; nt < 2; ++nt) {
    int gate = wcol * 2 + nt;
    int rowb = wm * 16 + lq * 4;
    const f32x4& a = nt ? acc1 : acc0;
#pragma unroll
    for (int r = 0; r < 4; ++r)
      sm.sg[gate * 1088 + (rowb + r) * 17 + lrow] = a[r];
  }
  FULLBAR();

  {
    const int erow = tid >> 3, ehp = (tid & 7) * 2;
    // epilogue-only global loads: issued after all counted VM ops (safe)
    float2 cp = *(const float2*)(c0l + (size_t)(m0 + erow) * 1024 + h0c + ehp);
    float cpa[2] = {cp.x, cp.y};
    float hva[2], cva[2];
#pragma unroll
    for (int e = 0; e < 2; ++e) {
      int hc = ehp + e;
      float gi = sm.sg[0 * 1088 + erow * 17 + hc] + bi[h0c + hc]          + bh[h0c + hc];
      float gf = sm.sg[1 * 1088 + erow * 17 + hc] + bi[1024 + h0c + hc]   + bh[1024 + h0c + hc];
      float gg = sm.sg[2 * 1088 + erow * 17 + hc] + bi[2048 + h0c + hc]   + bh[2048 + h0c + hc];
      float go = sm.sg[3 * 1088 + erow * 17 + hc] + bi[3072 + h0c + hc]   + bh[3072 + h0c + hc];
      float cn = sigm(gf) * cpa[e] + sigm(gi) * tanh_(gg);
      cva[e] = cn;
      hva[e] = sigm(go) * tanh_(cn);
    }
    float2 hv; hv.x = hva[0]; hv.y = hva[1];
    float2 cv; cv.x = cva[0]; cv.y = cva[1];
    *(float2*)(hout + (size_t)(m0 + erow) * 1024 + h0c + ehp) = hv;
    *(float2*)(cout + (size_t)(m0 + erow) * 1024 + h0c + ehp) = cv;
    if (apk_next) {  // packed bf16 h for next layer's A gathers
      int g = erow >> 3;
#pragma unroll
      for (int e = 0; e < 2; ++e) {
        int k = h0c + ehp + e;
        int cc = (k >> 3) & 7, j = k & 7;
        int i = (erow & 7) * 8 + ((cc ^ erow) & 7);
        apk_next[(size_t)mb * 131072 + (size_t)(k >> 6) * 4096 + g * 512 + i * 8 + j] =
            f2bf(hva[e]);
      }
    }
  }
}

extern "C" void kernel_launch(void* const* d_in, const int* in_sizes, int n_in,
                              void* d_out, int out_size, void* d_ws, size_t ws_size,
                              hipStream_t stream) {
  const float* x    = (const float*)d_in[0];
  const float* h0   = (const float*)d_in[1];
  const float* c0   = (const float*)d_in[2];
  const float* w_ih = (const float*)d_in[3];
  const float* w_hh = (const float*)d_in[4];
  const float* b_ih = (const float*)d_in[5];
  const float* b_hh = (const float*)d_in[6];
  float* out = (float*)d_out;

  ushort_t* Wpk = (ushort_t*)d_ws;              // 4 layers x 16 MB packed bf16 W
  ushort_t* Apk = Wpk + (size_t)4 * 8388608;    // 4 layers x 1 MB packed bf16 A

  // init: pack A (640 blocks) + ALL FOUR layers' weights (16384 blocks)
  pack_init<<<17024, 256, 0, stream>>>(x, h0, w_ih, w_hh, Wpk, Apk);

  const size_t BH = (size_t)BATCH * HID;
  for (int l = 0; l < NLAYER; ++l) {
    lstm_fused<<<dim3(64, 4), 512, 0, stream>>>(
        Apk + (size_t)l * 524288, Wpk + (size_t)l * 8388608,
        b_ih + (size_t)l * 4096, b_hh + (size_t)l * 4096,
        c0 + (size_t)l * BH,
        out + (size_t)l * BH, out + (size_t)NLAYER * BH + (size_t)l * BH,
        (l < NLAYER - 1) ? Apk + (size_t)(l + 1) * 524288 : (ushort_t*)nullptr);
  }
}